// Round 1
// 436.153 us; speedup vs baseline: 1.1321x; 1.1321x over previous
//
#include <hip/hip_runtime.h>
#include <hip/hip_bf16.h>
#include <stdint.h>
#include <math.h>

#define B_ 2
#define S_ 2048
#define E_ 2048
#define H_ 16
#define D_ 128
#define M_ (B_*S_)

typedef _Float16 half8 __attribute__((ext_vector_type(8)));
typedef _Float16 half4 __attribute__((ext_vector_type(4)));
typedef float    floatx4 __attribute__((ext_vector_type(4)));

// ---------------------------------------------------------------------------
// async global->LDS, 16B per lane. LDS dest must be wave-uniform base; HW
// writes lane L at base + L*16.
__device__ __forceinline__ void async_copy16(const void* g, void* lds_base) {
    __builtin_amdgcn_global_load_lds(
        (__attribute__((address_space(1))) void*)(uintptr_t)g,
        (__attribute__((address_space(3))) void*)(uint32_t)(uintptr_t)lds_base,
        16, 0, 0);
}

// ---------------------------------------------------------------------------
// fused fp32 -> fp16 cast for X + 4 weights, one launch (z selects tensor)
__global__ __launch_bounds__(256) void cast_all(
    const float* __restrict__ X,  const float* __restrict__ Wq,
    const float* __restrict__ Wk, const float* __restrict__ Wv,
    const float* __restrict__ Wo,
    _Float16* __restrict__ Xh,  _Float16* __restrict__ Wqh,
    _Float16* __restrict__ Wkh, _Float16* __restrict__ Wvh,
    _Float16* __restrict__ Woh)
{
    const int z = blockIdx.z;
    const float* in; _Float16* out; int n4;
    const int ME4 = M_*E_/4, EE4 = E_*E_/4;
    switch (z) {
        case 0: in = X;  out = Xh;  n4 = ME4; break;
        case 1: in = Wq; out = Wqh; n4 = EE4; break;
        case 2: in = Wk; out = Wkh; n4 = EE4; break;
        case 3: in = Wv; out = Wvh; n4 = EE4; break;
        default: in = Wo; out = Woh; n4 = EE4; break;
    }
    int i = blockIdx.x * 256 + threadIdx.x;
    if (i < n4) {
        floatx4 v = ((const floatx4*)in)[i];
        ((half4*)out)[i] = __builtin_convertvector(v, half4);
    }
}

// ---------------------------------------------------------------------------
// C[M,N] = A[M,K] · W[N,K]^T  (both K-contiguous row-major), f16 MFMA,
// m97 structure: 128x128 tile, BK=32, global_load_lds width=16.
// QKV variant: grid.z selects one of three weight/output pairs.
template<bool BIAS, typename OutT, int NW>
__global__ __launch_bounds__(256) void gemm_bt(
    const _Float16* __restrict__ A,
    const _Float16* __restrict__ W0, const _Float16* __restrict__ W1,
    const _Float16* __restrict__ W2,
    OutT* __restrict__ C0, OutT* __restrict__ C1, OutT* __restrict__ C2,
    const float* __restrict__ bias, int M, int N, int K)
{
    const _Float16* W = W0; OutT* C = C0;
    if (NW > 1) {
        if (blockIdx.z == 1) { W = W1; C = C1; }
        else if (blockIdx.z == 2) { W = W2; C = C2; }
    }
    __shared__ __align__(16) _Float16 As[128*32];
    __shared__ __align__(16) _Float16 Bs[128*32];
    const int tid  = threadIdx.x;
    const int lane = tid & 63;
    const int wave = tid >> 6;
    const int wm = wave >> 1, wn = wave & 1;      // 2x2 waves, 64x64 each
    const int fr = lane & 15, fg = lane >> 4;
    const int m0 = blockIdx.x * 128;
    const int n0 = blockIdx.y * 128;

    floatx4 acc[4][4] = {};

    for (int k0 = 0; k0 < K; k0 += 32) {
        __syncthreads();
#pragma unroll
        for (int i = 0; i < 2; ++i) {
            int c = wave * 2 + i;
            int e = c * 512 + lane * 8;           // element index in [128][32] tile
            int row = e >> 5, col = e & 31;
            async_copy16(A + (size_t)(m0 + row) * K + k0 + col, &As[c * 512]);
            async_copy16(W + (size_t)(n0 + row) * K + k0 + col, &Bs[c * 512]);
        }
        __syncthreads();

        half8 a[4], b[4];
#pragma unroll
        for (int t = 0; t < 4; ++t) {
            a[t] = *(const half8*)&As[(wm*64 + t*16 + fr) * 32 + fg*8];
            b[t] = *(const half8*)&Bs[(wn*64 + t*16 + fr) * 32 + fg*8];
        }
#pragma unroll
        for (int mt = 0; mt < 4; ++mt)
#pragma unroll
            for (int nt = 0; nt < 4; ++nt)
                acc[mt][nt] = __builtin_amdgcn_mfma_f32_16x16x32_f16(
                    a[mt], b[nt], acc[mt][nt], 0, 0, 0);
    }

#pragma unroll
    for (int mt = 0; mt < 4; ++mt)
#pragma unroll
        for (int nt = 0; nt < 4; ++nt) {
            int col = n0 + wn*64 + nt*16 + fr;
            float bv = BIAS ? bias[col] : 0.f;
#pragma unroll
            for (int r = 0; r < 4; ++r) {
                int row = m0 + wm*64 + mt*16 + fg*4 + r;
                C[(size_t)row * N + col] = (OutT)(acc[mt][nt][r] + bv);
            }
        }
}

// ---------------------------------------------------------------------------
// V [B,S,H*D] (f16) -> Vt [B*H, D, S] (f16), LDS-tiled 64x64 transpose
__global__ __launch_bounds__(256) void transpose_v(
    const _Float16* __restrict__ V, _Float16* __restrict__ Vt)
{
    __shared__ __align__(16) _Float16 t[64][72];
    const int bh = blockIdx.z;
    const int b = bh >> 4, h = bh & 15;
    const int s0 = blockIdx.x * 64, d0 = blockIdx.y * 64;
    const int tid = threadIdx.x;
#pragma unroll
    for (int i = 0; i < 2; ++i) {
        int e = (i*256 + tid) * 8;
        int row = e >> 6, col = e & 63;           // row = s, col = d
        *(half8*)&t[row][col] =
            *(const half8*)&V[(size_t)(b*S_ + s0 + row) * E_ + h*D_ + d0 + col];
    }
    __syncthreads();
#pragma unroll
    for (int i = 0; i < 2; ++i) {
        int e = (i*256 + tid) * 8;
        int dr = e >> 6, col = e & 63;            // dr = d, col = s
        half8 v;
#pragma unroll
        for (int j = 0; j < 8; ++j) v[j] = t[col + j][dr];
        *(half8*)&Vt[((size_t)bh * D_ + d0 + dr) * S_ + s0 + col] = v;
    }
}

// ---------------------------------------------------------------------------
// Block-cooperative causal flash attention.
// Each block owns TWO 64-row Q panels of one (b,h): hi panel (31-j) and lo
// panel (j). Lo's causal k-range is a subset of hi's, so one jt sweep serves
// both: per-block work = (32-j) + (j+1) = 33 half-panel units — uniform.
// K tile [64][128] and Vt tile [128][64] are staged into LDS per iteration via
// global_load_lds (coalesced, shared by all 4 waves and both panels) with an
// XOR swizzle (16B granules, slot ^= row&7) applied via the inverse-swizzled
// GLOBAL source address (linear LDS dest) so ds_read_b128 fragment reads are
// bank-conflict-free despite the 256B/128B row strides.
// Grid: 1-D 512, XCD-chunked: xcd = n&7 -> 4 heads per XCD (K+V = 4MB = L2).
__global__ __launch_bounds__(256, 2) void attn_causal_coop(
    const _Float16* __restrict__ Q, const _Float16* __restrict__ K,
    const _Float16* __restrict__ Vt, _Float16* __restrict__ O)
{
    const int n   = blockIdx.x;
    const int xcd = n & 7;
    const int idx = n >> 3;                    // 0..63
    const int bh  = xcd * 4 + (idx >> 4);      // 4 heads per XCD
    const int j   = idx & 15;                  // panel-pair index 0..15
    const int b = bh >> 4, h = bh & 15;
    const int tid = threadIdx.x, lane = tid & 63, wave = tid >> 6;
    const int fr = lane & 15, fg = lane >> 4;

    __shared__ __align__(16) _Float16 Ks[64*128];    // 16KB, swizzled
    __shared__ __align__(16) _Float16 Vs[128*64];    // 16KB, swizzled
    __shared__ __align__(16) _Float16 Ps[4][32*72];  // per-wave P strip

    const int rhi = (31 - j) * 64 + wave * 16;   // this wave's hi-panel rows
    const int rlo = j * 64 + wave * 16;          // this wave's lo-panel rows
    const int nkt = 32 - j;                      // k-tiles of 64

    // Q fragments: A[m=fr][k=fg*8+..], mt: 0=hi panel, 1=lo panel
    half8 qf[2][4];
    {
        const _Float16* qb0 = Q + ((size_t)(b*S_) + rhi) * E_ + h*D_;
        const _Float16* qb1 = Q + ((size_t)(b*S_) + rlo) * E_ + h*D_;
#pragma unroll
        for (int kk = 0; kk < 4; ++kk) {
            qf[0][kk] = *(const half8*)&qb0[(size_t)fr * E_ + kk*32 + fg*8];
            qf[1][kk] = *(const half8*)&qb1[(size_t)fr * E_ + kk*32 + fg*8];
        }
    }

    float m_i[2][4], l_i[2][4];
    floatx4 o[2][8] = {};
#pragma unroll
    for (int mt = 0; mt < 2; ++mt)
#pragma unroll
        for (int r = 0; r < 4; ++r) { m_i[mt][r] = -INFINITY; l_i[mt][r] = 0.f; }

    const float scale = 0.088388347648318447f;   // 1/sqrt(128)
    const _Float16* kg = K + (size_t)(b*S_) * E_ + h*D_;
    const _Float16* vg = Vt + (size_t)bh * D_ * S_;
    _Float16* ps = &Ps[wave][0];

    for (int jt = 0; jt < nkt; ++jt) {
        __syncthreads();                         // prev iter's LDS reads done
        // ---- stage K tile [64 rows][16 granules] (4 rounds x 4KB) --------
#pragma unroll
        for (int q = 0; q < 4; ++q) {
            int G = q*256 + tid;                 // granule index 0..1023
            int row = G >> 4, slot = G & 15;
            int c = slot ^ (row & 7);            // inverse swizzle on source
            async_copy16(kg + (size_t)(jt*64 + row) * E_ + c*8,
                         &Ks[(q*256 + wave*64) * 8]);
        }
        // ---- stage Vt tile [128 rows][8 granules] (4 rounds x 4KB) -------
#pragma unroll
        for (int q = 0; q < 4; ++q) {
            int G = q*256 + tid;
            int row = G >> 3, slot = G & 7;
            int c = slot ^ (row & 7);
            async_copy16(vg + (size_t)row * S_ + jt*64 + c*8,
                         &Vs[(q*256 + wave*64) * 8]);
        }
        __syncthreads();                         // vmcnt(0) drain -> tiles ready

        const bool lo_act = (jt <= j);

        // ---- S = Q K^T ---------------------------------------------------
        floatx4 sacc[2][4] = {};
#pragma unroll
        for (int kk = 0; kk < 4; ++kk) {
            half8 bf[4];
#pragma unroll
            for (int nt = 0; nt < 4; ++nt)
                bf[nt] = *(const half8*)
                    &Ks[(nt*16 + fr)*128 + (((kk*4 + fg) ^ (fr & 7)) * 8)];
#pragma unroll
            for (int nt = 0; nt < 4; ++nt)
                sacc[0][nt] = __builtin_amdgcn_mfma_f32_16x16x32_f16(
                    qf[0][kk], bf[nt], sacc[0][nt], 0, 0, 0);
            if (lo_act) {
#pragma unroll
                for (int nt = 0; nt < 4; ++nt)
                    sacc[1][nt] = __builtin_amdgcn_mfma_f32_16x16x32_f16(
                        qf[1][kk], bf[nt], sacc[1][nt], 0, 0, 0);
            }
        }

        // ---- online softmax ----------------------------------------------
        const int kc0 = jt*64 + fr;
#pragma unroll
        for (int mt = 0; mt < 2; ++mt) {
            if (mt == 1 && !lo_act) continue;
            const int qr0 = (mt ? rlo : rhi) + fg*4;
            float alpha[4];
#pragma unroll
            for (int r = 0; r < 4; ++r) {
                float mx = -INFINITY;
#pragma unroll
                for (int nt = 0; nt < 4; ++nt) {
                    float s = sacc[mt][nt][r] * scale;
                    s = (kc0 + nt*16 <= qr0 + r) ? s : -INFINITY;
                    sacc[mt][nt][r] = s;
                    mx = fmaxf(mx, s);
                }
                mx = fmaxf(mx, __shfl_xor(mx, 1));
                mx = fmaxf(mx, __shfl_xor(mx, 2));
                mx = fmaxf(mx, __shfl_xor(mx, 4));
                mx = fmaxf(mx, __shfl_xor(mx, 8));
                float mnew = fmaxf(m_i[mt][r], mx);
                alpha[r] = (m_i[mt][r] == -INFINITY) ? 0.f : __expf(m_i[mt][r] - mnew);
                float rs = 0.f;
#pragma unroll
                for (int nt = 0; nt < 4; ++nt) {
                    float p = __expf(sacc[mt][nt][r] - mnew);  // exp(-inf)=0 masks
                    sacc[mt][nt][r] = p;
                    rs += p;
                }
                rs += __shfl_xor(rs, 1);
                rs += __shfl_xor(rs, 2);
                rs += __shfl_xor(rs, 4);
                rs += __shfl_xor(rs, 8);
                l_i[mt][r] = alpha[r] * l_i[mt][r] + rs;
                m_i[mt][r] = mnew;
            }
#pragma unroll
            for (int dt = 0; dt < 8; ++dt)
#pragma unroll
                for (int r = 0; r < 4; ++r) o[mt][dt][r] *= alpha[r];

            // P: C-layout -> A-layout, wave-private LDS strip
#pragma unroll
            for (int nt = 0; nt < 4; ++nt)
#pragma unroll
                for (int r = 0; r < 4; ++r)
                    ps[(mt*16 + fg*4 + r)*72 + nt*16 + fr] = (_Float16)sacc[mt][nt][r];
        }
        __asm__ __volatile__("s_waitcnt lgkmcnt(0)" ::: "memory");

        // ---- O += P · V (Vs rows are B-layout, k = seq contiguous) -------
#pragma unroll
        for (int kk = 0; kk < 2; ++kk) {
            half8 pf0 = *(const half8*)&ps[(fr)*72 + kk*32 + fg*8];
            half8 pf1 = *(const half8*)&ps[(16 + fr)*72 + kk*32 + fg*8];
#pragma unroll
            for (int dt = 0; dt < 8; ++dt) {
                half8 vf = *(const half8*)
                    &Vs[(dt*16 + fr)*64 + (((kk*4 + fg) ^ (fr & 7)) * 8)];
                o[0][dt] = __builtin_amdgcn_mfma_f32_16x16x32_f16(
                    pf0, vf, o[0][dt], 0, 0, 0);
                if (lo_act)
                    o[1][dt] = __builtin_amdgcn_mfma_f32_16x16x32_f16(
                        pf1, vf, o[1][dt], 0, 0, 0);
            }
        }
    }

    // ---- epilogue ---------------------------------------------------------
#pragma unroll
    for (int mt = 0; mt < 2; ++mt) {
        const int rbase = mt ? rlo : rhi;
        _Float16* ob = O + ((size_t)(b*S_) + rbase) * E_ + h*D_;
#pragma unroll
        for (int r = 0; r < 4; ++r) {
            float inv = 1.f / l_i[mt][r];
#pragma unroll
            for (int dt = 0; dt < 8; ++dt)
                ob[(size_t)(fg*4 + r) * E_ + dt*16 + fr] = (_Float16)(o[mt][dt][r] * inv);
        }
    }
}

// ---------------------------------------------------------------------------
extern "C" void kernel_launch(void* const* d_in, const int* in_sizes, int n_in,
                              void* d_out, int out_size, void* d_ws, size_t ws_size,
                              hipStream_t stream) {
    const float* X  = (const float*)d_in[0];
    const float* Wq = (const float*)d_in[1];
    const float* Wk = (const float*)d_in[2];
    const float* Wv = (const float*)d_in[3];
    const float* Wo = (const float*)d_in[4];
    const float* bo = (const float*)d_in[5];
    float* out = (float*)d_out;

    const size_t ME = (size_t)M_ * E_;   // 8,388,608
    const size_t EE = (size_t)E_ * E_;   // 4,194,304
    _Float16* ws  = (_Float16*)d_ws;
    _Float16* Xh  = ws;
    _Float16* Wqh = Xh  + ME;
    _Float16* Wkh = Wqh + EE;
    _Float16* Wvh = Wkh + EE;
    _Float16* Woh = Wvh + EE;
    _Float16* Qh  = Woh + EE;
    _Float16* Kh  = Qh  + ME;
    _Float16* Vh  = Kh  + ME;
    _Float16* Vth = Xh;   // Xh dead after the QKV GEMMs
    _Float16* Oh  = Vh;   // V dead after the transpose

    cast_all<<<dim3(ME/4/256, 1, 5), dim3(256), 0, stream>>>(
        X, Wq, Wk, Wv, Wo, Xh, Wqh, Wkh, Wvh, Woh);

    gemm_bt<false, _Float16, 3><<<dim3(M_/128, E_/128, 3), dim3(256), 0, stream>>>(
        Xh, Wqh, Wkh, Wvh, Qh, Kh, Vh, nullptr, M_, E_, E_);

    transpose_v<<<dim3(S_/64, D_/64, B_*H_), dim3(256), 0, stream>>>(Vh, Vth);

    attn_causal_coop<<<dim3(512), dim3(256), 0, stream>>>(Qh, Kh, Vth, Oh);

    gemm_bt<true, float, 1><<<dim3(M_/128, E_/128, 1), dim3(256), 0, stream>>>(
        Oh, Woh, nullptr, nullptr, out, nullptr, nullptr, bo, M_, E_, E_);
}

// Round 2
// 404.490 us; speedup vs baseline: 1.2208x; 1.0783x over previous
//
#include <hip/hip_runtime.h>
#include <hip/hip_bf16.h>
#include <stdint.h>
#include <math.h>

#define B_ 2
#define S_ 2048
#define E_ 2048
#define H_ 16
#define D_ 128
#define M_ (B_*S_)

typedef _Float16 half8 __attribute__((ext_vector_type(8)));
typedef _Float16 half4 __attribute__((ext_vector_type(4)));
typedef float    floatx4 __attribute__((ext_vector_type(4)));

// ---------------------------------------------------------------------------
// async global->LDS, 16B per lane. LDS dest must be wave-uniform base; HW
// writes lane L at base + L*16.
__device__ __forceinline__ void async_copy16(const void* g, void* lds_base) {
    __builtin_amdgcn_global_load_lds(
        (__attribute__((address_space(1))) void*)(uintptr_t)g,
        (__attribute__((address_space(3))) void*)(uint32_t)(uintptr_t)lds_base,
        16, 0, 0);
}

// ---------------------------------------------------------------------------
// fused fp32 -> fp16 cast for X + 4 weights, one launch (z selects tensor)
__global__ __launch_bounds__(256) void cast_all(
    const float* __restrict__ X,  const float* __restrict__ Wq,
    const float* __restrict__ Wk, const float* __restrict__ Wv,
    const float* __restrict__ Wo,
    _Float16* __restrict__ Xh,  _Float16* __restrict__ Wqh,
    _Float16* __restrict__ Wkh, _Float16* __restrict__ Wvh,
    _Float16* __restrict__ Woh)
{
    const int z = blockIdx.z;
    const float* in; _Float16* out; int n4;
    const int ME4 = M_*E_/4, EE4 = E_*E_/4;
    switch (z) {
        case 0: in = X;  out = Xh;  n4 = ME4; break;
        case 1: in = Wq; out = Wqh; n4 = EE4; break;
        case 2: in = Wk; out = Wkh; n4 = EE4; break;
        case 3: in = Wv; out = Wvh; n4 = EE4; break;
        default: in = Wo; out = Woh; n4 = EE4; break;
    }
    int i = blockIdx.x * 256 + threadIdx.x;
    if (i < n4) {
        floatx4 v = ((const floatx4*)in)[i];
        ((half4*)out)[i] = __builtin_convertvector(v, half4);
    }
}

// ---------------------------------------------------------------------------
// Phased-pipeline GEMM: C[M,N] = A[M,K] · W[N,K]^T, f16 MFMA, fp32 acc.
// BM=128, BN=256, BK=64, 512 threads = 8 waves (2M x 4N), 64x64 per wave.
// 3-buffer LDS ring (144KB): while computing tile t (4 phases), tile t+2 is
// staged via global_load_lds into the buffer last read at t-1 (race-free with
// raw s_barrier, no vmcnt drain). Boundary wait = counted vmcnt(6) (t+1's 6
// loads stay in flight). XOR swizzle (granule ^= row&7) applied on the global
// SOURCE address (linear LDS dest) and on the ds_read address -> conflict-free
// ds_read_b128. s_setprio(1) around MFMA clusters.
// Requires: M%128==0, N==2048 (n_tile = bx&7), K%64==0.
// grid = (256, NW); blockIdx.y selects weight/output pair.
#define GBUF (128*64 + 256*64)   // f16 elements per ring buffer (48KB)

__device__ __forceinline__ void stage512(
    const _Float16* __restrict__ gsrc, int ldk,
    _Float16* lbase, int slot0, int wave, int lane)
{
    int slot = slot0 + wave*64 + lane;
    int row  = slot >> 3;
    int sg   = (slot & 7) ^ (row & 7);        // inverse swizzle on source
    async_copy16(gsrc + (size_t)row * ldk + sg * 8,
                 lbase + (slot0 + wave*64) * 8);
}

template<bool BIAS, typename OutT, int NW>
__global__ __launch_bounds__(512, 2) void gemm_bt(
    const _Float16* __restrict__ A,
    const _Float16* __restrict__ W0, const _Float16* __restrict__ W1,
    const _Float16* __restrict__ W2,
    OutT* __restrict__ C0, OutT* __restrict__ C1, OutT* __restrict__ C2,
    const float* __restrict__ bias, int M, int N, int K)
{
    const _Float16* W = W0; OutT* C = C0;
    if (NW > 1) {
        if (blockIdx.y == 1) { W = W1; C = C1; }
        else if (blockIdx.y == 2) { W = W2; C = C2; }
    }
    __shared__ __align__(16) _Float16 sm[3 * GBUF];   // 147456 B

    const int tid  = threadIdx.x;
    const int lane = tid & 63;
    const int wave = tid >> 6;
    const int wm = wave >> 2, wn = wave & 3;          // 2x4 waves, 64x64 each
    const int fr = lane & 15, fg = lane >> 4;

    const int bx = blockIdx.x;
    const int n_tile = bx & 7;                        // XCD-chunk: L2-resident B panel
    const int m_tile = bx >> 3;
    const int m0 = m_tile * 128;
    const int n0 = n_tile * 256;

    const int NT = K >> 6;                            // K-tiles of 64

    // ---- prologue: stage tiles 0 and 1 -----------------------------------
#pragma unroll
    for (int pt = 0; pt < 2; ++pt) {
        _Float16* ab = &sm[pt * GBUF];
        _Float16* bb = ab + 128*64;
        const _Float16* Ag = A + (size_t)m0 * K + pt*64;
        const _Float16* Wg = W + (size_t)n0 * K + pt*64;
        stage512(Ag, K, ab, 0,    wave, lane);
        stage512(Ag, K, ab, 512,  wave, lane);
        stage512(Wg, K, bb, 0,    wave, lane);
        stage512(Wg, K, bb, 512,  wave, lane);
        stage512(Wg, K, bb, 1024, wave, lane);
        stage512(Wg, K, bb, 1536, wave, lane);
    }

    floatx4 acc[4][4] = {};

    for (int t = 0; t < NT; ++t) {
        // ---- tile boundary: counted wait, never a full drain in steady ----
        if (t + 1 < NT) { __asm__ __volatile__("s_waitcnt vmcnt(6)" ::: "memory"); }
        else            { __asm__ __volatile__("s_waitcnt vmcnt(0)" ::: "memory"); }
        __builtin_amdgcn_sched_barrier(0);
        __builtin_amdgcn_s_barrier();      // all waves' tile-t loads landed

        const _Float16* Ab = &sm[(t % 3) * GBUF];
        const _Float16* Bb = Ab + 128*64;
        const bool pf = (t + 2 < NT);
        _Float16* pab = &sm[((t + 2) % 3) * GBUF];
        _Float16* pbb = pab + 128*64;
        const _Float16* pAg = A + (size_t)m0 * K + (t + 2)*64;
        const _Float16* pWg = W + (size_t)n0 * K + (t + 2)*64;

        half8 af[4][2];

        // ---- 4 phases: one N-frag column each, 8 MFMA per phase ----------
#pragma unroll
        for (int p = 0; p < 4; ++p) {
            if (p == 0) {
                // all A fragments, held in registers across phases
#pragma unroll
                for (int mt = 0; mt < 4; ++mt)
#pragma unroll
                    for (int kk = 0; kk < 2; ++kk) {
                        int row = wm*64 + mt*16 + fr;
                        int g = (kk*4 + fg) ^ (row & 7);
                        af[mt][kk] = *(const half8*)&Ab[row*64 + g*8];
                    }
            }
            half8 bf[2];
            {
                int row = wn*64 + p*16 + fr;
#pragma unroll
                for (int kk = 0; kk < 2; ++kk) {
                    int g = (kk*4 + fg) ^ (row & 7);
                    bf[kk] = *(const half8*)&Bb[row*64 + g*8];
                }
            }
            // interleaved staging of tile t+2: 2,2,1,1 rounds across phases
            if (pf) {
                if (p == 0) {
                    stage512(pAg, K, pab, 0,   wave, lane);
                    stage512(pAg, K, pab, 512, wave, lane);
                } else if (p == 1) {
                    stage512(pWg, K, pbb, 0,   wave, lane);
                    stage512(pWg, K, pbb, 512, wave, lane);
                } else if (p == 2) {
                    stage512(pWg, K, pbb, 1024, wave, lane);
                } else {
                    stage512(pWg, K, pbb, 1536, wave, lane);
                }
            }
            __builtin_amdgcn_s_barrier();
            __asm__ __volatile__("s_waitcnt lgkmcnt(0)" ::: "memory");
            __builtin_amdgcn_sched_barrier(0);
            __builtin_amdgcn_s_setprio(1);
#pragma unroll
            for (int kk = 0; kk < 2; ++kk)
#pragma unroll
                for (int mt = 0; mt < 4; ++mt)
                    acc[mt][p] = __builtin_amdgcn_mfma_f32_16x16x32_f16(
                        af[mt][kk], bf[kk], acc[mt][p], 0, 0, 0);
            __builtin_amdgcn_s_setprio(0);
            __builtin_amdgcn_s_barrier();
        }
    }

    // ---- epilogue ---------------------------------------------------------
#pragma unroll
    for (int mt = 0; mt < 4; ++mt)
#pragma unroll
        for (int nt = 0; nt < 4; ++nt) {
            int col = n0 + wn*64 + nt*16 + fr;
            float bv = BIAS ? bias[col] : 0.f;
#pragma unroll
            for (int r = 0; r < 4; ++r) {
                int row = m0 + wm*64 + mt*16 + fg*4 + r;
                C[(size_t)row * N + col] = (OutT)(acc[mt][nt][r] + bv);
            }
        }
}

// ---------------------------------------------------------------------------
// V [B,S,H*D] (f16) -> Vt [B*H, D, S] (f16), LDS-tiled 64x64 transpose
__global__ __launch_bounds__(256) void transpose_v(
    const _Float16* __restrict__ V, _Float16* __restrict__ Vt)
{
    __shared__ __align__(16) _Float16 t[64][72];
    const int bh = blockIdx.z;
    const int b = bh >> 4, h = bh & 15;
    const int s0 = blockIdx.x * 64, d0 = blockIdx.y * 64;
    const int tid = threadIdx.x;
#pragma unroll
    for (int i = 0; i < 2; ++i) {
        int e = (i*256 + tid) * 8;
        int row = e >> 6, col = e & 63;           // row = s, col = d
        *(half8*)&t[row][col] =
            *(const half8*)&V[(size_t)(b*S_ + s0 + row) * E_ + h*D_ + d0 + col];
    }
    __syncthreads();
#pragma unroll
    for (int i = 0; i < 2; ++i) {
        int e = (i*256 + tid) * 8;
        int dr = e >> 6, col = e & 63;            // dr = d, col = s
        half8 v;
#pragma unroll
        for (int j = 0; j < 8; ++j) v[j] = t[col + j][dr];
        *(half8*)&Vt[((size_t)bh * D_ + d0 + dr) * S_ + s0 + col] = v;
    }
}

// ---------------------------------------------------------------------------
// Block-cooperative causal flash attention (unchanged from round 1).
__global__ __launch_bounds__(256, 2) void attn_causal_coop(
    const _Float16* __restrict__ Q, const _Float16* __restrict__ K,
    const _Float16* __restrict__ Vt, _Float16* __restrict__ O)
{
    const int n   = blockIdx.x;
    const int xcd = n & 7;
    const int idx = n >> 3;                    // 0..63
    const int bh  = xcd * 4 + (idx >> 4);      // 4 heads per XCD
    const int j   = idx & 15;                  // panel-pair index 0..15
    const int b = bh >> 4, h = bh & 15;
    const int tid = threadIdx.x, lane = tid & 63, wave = tid >> 6;
    const int fr = lane & 15, fg = lane >> 4;

    __shared__ __align__(16) _Float16 Ks[64*128];    // 16KB, swizzled
    __shared__ __align__(16) _Float16 Vs[128*64];    // 16KB, swizzled
    __shared__ __align__(16) _Float16 Ps[4][32*72];  // per-wave P strip

    const int rhi = (31 - j) * 64 + wave * 16;   // this wave's hi-panel rows
    const int rlo = j * 64 + wave * 16;          // this wave's lo-panel rows
    const int nkt = 32 - j;                      // k-tiles of 64

    // Q fragments: A[m=fr][k=fg*8+..], mt: 0=hi panel, 1=lo panel
    half8 qf[2][4];
    {
        const _Float16* qb0 = Q + ((size_t)(b*S_) + rhi) * E_ + h*D_;
        const _Float16* qb1 = Q + ((size_t)(b*S_) + rlo) * E_ + h*D_;
#pragma unroll
        for (int kk = 0; kk < 4; ++kk) {
            qf[0][kk] = *(const half8*)&qb0[(size_t)fr * E_ + kk*32 + fg*8];
            qf[1][kk] = *(const half8*)&qb1[(size_t)fr * E_ + kk*32 + fg*8];
        }
    }

    float m_i[2][4], l_i[2][4];
    floatx4 o[2][8] = {};
#pragma unroll
    for (int mt = 0; mt < 2; ++mt)
#pragma unroll
        for (int r = 0; r < 4; ++r) { m_i[mt][r] = -INFINITY; l_i[mt][r] = 0.f; }

    const float scale = 0.088388347648318447f;   // 1/sqrt(128)
    const _Float16* kg = K + (size_t)(b*S_) * E_ + h*D_;
    const _Float16* vg = Vt + (size_t)bh * D_ * S_;
    _Float16* ps = &Ps[wave][0];

    for (int jt = 0; jt < nkt; ++jt) {
        __syncthreads();                         // prev iter's LDS reads done
        // ---- stage K tile [64 rows][16 granules] (4 rounds x 4KB) --------
#pragma unroll
        for (int q = 0; q < 4; ++q) {
            int G = q*256 + tid;                 // granule index 0..1023
            int row = G >> 4, slot = G & 15;
            int c = slot ^ (row & 7);            // inverse swizzle on source
            async_copy16(kg + (size_t)(jt*64 + row) * E_ + c*8,
                         &Ks[(q*256 + wave*64) * 8]);
        }
        // ---- stage Vt tile [128 rows][8 granules] (4 rounds x 4KB) -------
#pragma unroll
        for (int q = 0; q < 4; ++q) {
            int G = q*256 + tid;
            int row = G >> 3, slot = G & 7;
            int c = slot ^ (row & 7);
            async_copy16(vg + (size_t)row * S_ + jt*64 + c*8,
                         &Vs[(q*256 + wave*64) * 8]);
        }
        __syncthreads();                         // vmcnt(0) drain -> tiles ready

        const bool lo_act = (jt <= j);

        // ---- S = Q K^T ---------------------------------------------------
        floatx4 sacc[2][4] = {};
#pragma unroll
        for (int kk = 0; kk < 4; ++kk) {
            half8 bf[4];
#pragma unroll
            for (int nt = 0; nt < 4; ++nt)
                bf[nt] = *(const half8*)
                    &Ks[(nt*16 + fr)*128 + (((kk*4 + fg) ^ (fr & 7)) * 8)];
#pragma unroll
            for (int nt = 0; nt < 4; ++nt)
                sacc[0][nt] = __builtin_amdgcn_mfma_f32_16x16x32_f16(
                    qf[0][kk], bf[nt], sacc[0][nt], 0, 0, 0);
            if (lo_act) {
#pragma unroll
                for (int nt = 0; nt < 4; ++nt)
                    sacc[1][nt] = __builtin_amdgcn_mfma_f32_16x16x32_f16(
                        qf[1][kk], bf[nt], sacc[1][nt], 0, 0, 0);
            }
        }

        // ---- online softmax ----------------------------------------------
        const int kc0 = jt*64 + fr;
#pragma unroll
        for (int mt = 0; mt < 2; ++mt) {
            if (mt == 1 && !lo_act) continue;
            const int qr0 = (mt ? rlo : rhi) + fg*4;
            float alpha[4];
#pragma unroll
            for (int r = 0; r < 4; ++r) {
                float mx = -INFINITY;
#pragma unroll
                for (int nt = 0; nt < 4; ++nt) {
                    float s = sacc[mt][nt][r] * scale;
                    s = (kc0 + nt*16 <= qr0 + r) ? s : -INFINITY;
                    sacc[mt][nt][r] = s;
                    mx = fmaxf(mx, s);
                }
                mx = fmaxf(mx, __shfl_xor(mx, 1));
                mx = fmaxf(mx, __shfl_xor(mx, 2));
                mx = fmaxf(mx, __shfl_xor(mx, 4));
                mx = fmaxf(mx, __shfl_xor(mx, 8));
                float mnew = fmaxf(m_i[mt][r], mx);
                alpha[r] = (m_i[mt][r] == -INFINITY) ? 0.f : __expf(m_i[mt][r] - mnew);
                float rs = 0.f;
#pragma unroll
                for (int nt = 0; nt < 4; ++nt) {
                    float p = __expf(sacc[mt][nt][r] - mnew);  // exp(-inf)=0 masks
                    sacc[mt][nt][r] = p;
                    rs += p;
                }
                rs += __shfl_xor(rs, 1);
                rs += __shfl_xor(rs, 2);
                rs += __shfl_xor(rs, 4);
                rs += __shfl_xor(rs, 8);
                l_i[mt][r] = alpha[r] * l_i[mt][r] + rs;
                m_i[mt][r] = mnew;
            }
#pragma unroll
            for (int dt = 0; dt < 8; ++dt)
#pragma unroll
                for (int r = 0; r < 4; ++r) o[mt][dt][r] *= alpha[r];

            // P: C-layout -> A-layout, wave-private LDS strip
#pragma unroll
            for (int nt = 0; nt < 4; ++nt)
#pragma unroll
                for (int r = 0; r < 4; ++r)
                    ps[(mt*16 + fg*4 + r)*72 + nt*16 + fr] = (_Float16)sacc[mt][nt][r];
        }
        __asm__ __volatile__("s_waitcnt lgkmcnt(0)" ::: "memory");

        // ---- O += P · V (Vs rows are B-layout, k = seq contiguous) -------
#pragma unroll
        for (int kk = 0; kk < 2; ++kk) {
            half8 pf0 = *(const half8*)&ps[(fr)*72 + kk*32 + fg*8];
            half8 pf1 = *(const half8*)&ps[(16 + fr)*72 + kk*32 + fg*8];
#pragma unroll
            for (int dt = 0; dt < 8; ++dt) {
                half8 vf = *(const half8*)
                    &Vs[(dt*16 + fr)*64 + (((kk*4 + fg) ^ (fr & 7)) * 8)];
                o[0][dt] = __builtin_amdgcn_mfma_f32_16x16x32_f16(
                    pf0, vf, o[0][dt], 0, 0, 0);
                if (lo_act)
                    o[1][dt] = __builtin_amdgcn_mfma_f32_16x16x32_f16(
                        pf1, vf, o[1][dt], 0, 0, 0);
            }
        }
    }

    // ---- epilogue ---------------------------------------------------------
#pragma unroll
    for (int mt = 0; mt < 2; ++mt) {
        const int rbase = mt ? rlo : rhi;
        _Float16* ob = O + ((size_t)(b*S_) + rbase) * E_ + h*D_;
#pragma unroll
        for (int r = 0; r < 4; ++r) {
            float inv = 1.f / l_i[mt][r];
#pragma unroll
            for (int dt = 0; dt < 8; ++dt)
                ob[(size_t)(fg*4 + r) * E_ + dt*16 + fr] = (_Float16)(o[mt][dt][r] * inv);
        }
    }
}

// ---------------------------------------------------------------------------
extern "C" void kernel_launch(void* const* d_in, const int* in_sizes, int n_in,
                              void* d_out, int out_size, void* d_ws, size_t ws_size,
                              hipStream_t stream) {
    const float* X  = (const float*)d_in[0];
    const float* Wq = (const float*)d_in[1];
    const float* Wk = (const float*)d_in[2];
    const float* Wv = (const float*)d_in[3];
    const float* Wo = (const float*)d_in[4];
    const float* bo = (const float*)d_in[5];
    float* out = (float*)d_out;

    const size_t ME = (size_t)M_ * E_;   // 8,388,608
    const size_t EE = (size_t)E_ * E_;   // 4,194,304
    _Float16* ws  = (_Float16*)d_ws;
    _Float16* Xh  = ws;
    _Float16* Wqh = Xh  + ME;
    _Float16* Wkh = Wqh + EE;
    _Float16* Wvh = Wkh + EE;
    _Float16* Woh = Wvh + EE;
    _Float16* Qh  = Woh + EE;
    _Float16* Kh  = Qh  + ME;
    _Float16* Vh  = Kh  + ME;
    _Float16* Vth = Xh;   // Xh dead after the QKV GEMMs
    _Float16* Oh  = Vh;   // V dead after the transpose

    cast_all<<<dim3(ME/4/256, 1, 5), dim3(256), 0, stream>>>(
        X, Wq, Wk, Wv, Wo, Xh, Wqh, Wkh, Wvh, Woh);

    gemm_bt<false, _Float16, 3><<<dim3(256, 3), dim3(512), 0, stream>>>(
        Xh, Wqh, Wkh, Wvh, Qh, Kh, Vh, nullptr, M_, E_, E_);

    transpose_v<<<dim3(S_/64, D_/64, B_*H_), dim3(256), 0, stream>>>(Vh, Vth);

    attn_causal_coop<<<dim3(512), dim3(256), 0, stream>>>(Qh, Kh, Vth, Oh);

    gemm_bt<true, float, 1><<<dim3(256, 1), dim3(512), 0, stream>>>(
        Oh, Woh, nullptr, nullptr, out, nullptr, nullptr, bo, M_, E_, E_);
}

// Round 3
// 385.052 us; speedup vs baseline: 1.2824x; 1.0505x over previous
//
#include <hip/hip_runtime.h>
#include <hip/hip_bf16.h>
#include <stdint.h>
#include <math.h>

#define B_ 2
#define S_ 2048
#define E_ 2048
#define H_ 16
#define D_ 128
#define M_ (B_*S_)

typedef _Float16 half8 __attribute__((ext_vector_type(8)));
typedef _Float16 half4 __attribute__((ext_vector_type(4)));
typedef float    floatx4 __attribute__((ext_vector_type(4)));

// ---------------------------------------------------------------------------
// async global->LDS, 16B per lane. LDS dest must be wave-uniform base; HW
// writes lane L at base + L*16.
__device__ __forceinline__ void async_copy16(const void* g, void* lds_base) {
    __builtin_amdgcn_global_load_lds(
        (__attribute__((address_space(1))) void*)(uintptr_t)g,
        (__attribute__((address_space(3))) void*)(uint32_t)(uintptr_t)lds_base,
        16, 0, 0);
}

// ---------------------------------------------------------------------------
// fused fp32 -> fp16 cast for X + 4 weights, one launch (z selects tensor)
__global__ __launch_bounds__(256) void cast_all(
    const float* __restrict__ X,  const float* __restrict__ Wq,
    const float* __restrict__ Wk, const float* __restrict__ Wv,
    const float* __restrict__ Wo,
    _Float16* __restrict__ Xh,  _Float16* __restrict__ Wqh,
    _Float16* __restrict__ Wkh, _Float16* __restrict__ Wvh,
    _Float16* __restrict__ Woh)
{
    const int z = blockIdx.z;
    const float* in; _Float16* out; int n4;
    const int ME4 = M_*E_/4, EE4 = E_*E_/4;
    switch (z) {
        case 0: in = X;  out = Xh;  n4 = ME4; break;
        case 1: in = Wq; out = Wqh; n4 = EE4; break;
        case 2: in = Wk; out = Wkh; n4 = EE4; break;
        case 3: in = Wv; out = Wvh; n4 = EE4; break;
        default: in = Wo; out = Woh; n4 = EE4; break;
    }
    int i = blockIdx.x * 256 + threadIdx.x;
    if (i < n4) {
        floatx4 v = ((const floatx4*)in)[i];
        ((half4*)out)[i] = __builtin_convertvector(v, half4);
    }
}

// ---------------------------------------------------------------------------
// Free-flow pipelined GEMM: C[M,N] = A[M,K] · W[N,K]^T, f16 MFMA, fp32 acc.
// BM=128, BN=256, BK=64, 512 threads = 8 waves (2M x 4N), 64x64 per wave.
// 3-buffer LDS ring (144KB). Exactly ONE s_barrier + ONE counted vmcnt per
// K-tile; the tile interior (16 ds_read_b128 + 6 global_load_lds + 32 MFMA
// per wave) is fully compiler-scheduled (fine-grained lgkmcnt, loads in
// flight across the barrier — AITER-style, never vmcnt(0) in steady state).
// Race-freedom: writes during tile t+1 go to buffer t%3; every wave's reads
// of buffer t%3 returned before it arrives at the t+1 boundary barrier
// (lgkmcnt waits precede the MFMAs that precede the barrier).
// XOR swizzle (granule ^= row&7) on global source + ds_read addr (rule 21).
// Requires: M%128==0, N==2048 (n_tile = bx&7 -> XCD-resident B panel), K%64==0.
// grid = (256, NW); blockIdx.y selects weight/output pair.
#define GBUF (128*64 + 256*64)   // f16 elements per ring buffer (48KB)

__device__ __forceinline__ void stage512(
    const _Float16* __restrict__ gsrc, int ldk,
    _Float16* lbase, int slot0, int wave, int lane)
{
    int slot = slot0 + wave*64 + lane;
    int row  = slot >> 3;
    int sg   = (slot & 7) ^ (row & 7);        // inverse swizzle on source
    async_copy16(gsrc + (size_t)row * ldk + sg * 8,
                 lbase + (slot0 + wave*64) * 8);
}

template<bool BIAS, typename OutT, int NW>
__global__ __launch_bounds__(512, 2) void gemm_bt(
    const _Float16* __restrict__ A,
    const _Float16* __restrict__ W0, const _Float16* __restrict__ W1,
    const _Float16* __restrict__ W2,
    OutT* __restrict__ C0, OutT* __restrict__ C1, OutT* __restrict__ C2,
    const float* __restrict__ bias, int M, int N, int K)
{
    const _Float16* W = W0; OutT* C = C0;
    if (NW > 1) {
        if (blockIdx.y == 1) { W = W1; C = C1; }
        else if (blockIdx.y == 2) { W = W2; C = C2; }
    }
    __shared__ __align__(16) _Float16 sm[3 * GBUF];   // 147456 B

    const int tid  = threadIdx.x;
    const int lane = tid & 63;
    const int wave = tid >> 6;
    const int wm = wave >> 2, wn = wave & 3;          // 2x4 waves, 64x64 each
    const int fr = lane & 15, fg = lane >> 4;

    const int bx = blockIdx.x;
    const int n_tile = bx & 7;                        // XCD-chunk: L2-resident B panel
    const int m_tile = bx >> 3;
    const int m0 = m_tile * 128;
    const int n0 = n_tile * 256;

    const int NT = K >> 6;                            // K-tiles of 64

    // ---- prologue: stage tiles 0 and 1 -----------------------------------
#pragma unroll
    for (int pt = 0; pt < 2; ++pt) {
        _Float16* ab = &sm[pt * GBUF];
        _Float16* bb = ab + 128*64;
        const _Float16* Ag = A + (size_t)m0 * K + pt*64;
        const _Float16* Wg = W + (size_t)n0 * K + pt*64;
        stage512(Ag, K, ab, 0,    wave, lane);
        stage512(Ag, K, ab, 512,  wave, lane);
        stage512(Wg, K, bb, 0,    wave, lane);
        stage512(Wg, K, bb, 512,  wave, lane);
        stage512(Wg, K, bb, 1024, wave, lane);
        stage512(Wg, K, bb, 1536, wave, lane);
    }

    floatx4 acc[4][4] = {};

    for (int t = 0; t < NT; ++t) {
        // ---- tile boundary: counted wait + single barrier ----------------
        if (t + 1 < NT) { __asm__ __volatile__("s_waitcnt vmcnt(6)" ::: "memory"); }
        else            { __asm__ __volatile__("s_waitcnt vmcnt(0)" ::: "memory"); }
        __builtin_amdgcn_sched_barrier(0);
        __builtin_amdgcn_s_barrier();      // all waves' tile-t loads landed
        __builtin_amdgcn_sched_barrier(0);

        const _Float16* Ab = &sm[(t % 3) * GBUF];
        const _Float16* Bb = Ab + 128*64;
        const bool pf = (t + 2 < NT);
        _Float16* pab = &sm[((t + 2) % 3) * GBUF];
        _Float16* pbb = pab + 128*64;
        const _Float16* pAg = A + (size_t)m0 * K + (t + 2)*64;
        const _Float16* pWg = W + (size_t)n0 * K + (t + 2)*64;

        // ---- fragment loads (compiler-scheduled, fine-grained lgkmcnt) ---
        half8 af[4][2], bf[4][2];
#pragma unroll
        for (int mt = 0; mt < 4; ++mt)
#pragma unroll
            for (int kk = 0; kk < 2; ++kk) {
                int row = wm*64 + mt*16 + fr;
                int g = (kk*4 + fg) ^ (row & 7);
                af[mt][kk] = *(const half8*)&Ab[row*64 + g*8];
            }
#pragma unroll
        for (int nt = 0; nt < 4; ++nt)
#pragma unroll
            for (int kk = 0; kk < 2; ++kk) {
                int row = wn*64 + nt*16 + fr;
                int g = (kk*4 + fg) ^ (row & 7);
                bf[nt][kk] = *(const half8*)&Bb[row*64 + g*8];
            }

        // ---- issue tile t+2 staging (stays in flight across barrier) -----
        if (pf) {
            stage512(pAg, K, pab, 0,    wave, lane);
            stage512(pAg, K, pab, 512,  wave, lane);
            stage512(pWg, K, pbb, 0,    wave, lane);
            stage512(pWg, K, pbb, 512,  wave, lane);
            stage512(pWg, K, pbb, 1024, wave, lane);
            stage512(pWg, K, pbb, 1536, wave, lane);
        }

        // ---- 32 MFMA ------------------------------------------------------
        __builtin_amdgcn_s_setprio(1);
#pragma unroll
        for (int kk = 0; kk < 2; ++kk)
#pragma unroll
            for (int nt = 0; nt < 4; ++nt)
#pragma unroll
                for (int mt = 0; mt < 4; ++mt)
                    acc[mt][nt] = __builtin_amdgcn_mfma_f32_16x16x32_f16(
                        af[mt][kk], bf[nt][kk], acc[mt][nt], 0, 0, 0);
        __builtin_amdgcn_s_setprio(0);
    }

    // ---- epilogue ---------------------------------------------------------
#pragma unroll
    for (int mt = 0; mt < 4; ++mt)
#pragma unroll
        for (int nt = 0; nt < 4; ++nt) {
            int col = n0 + wn*64 + nt*16 + fr;
            float bv = BIAS ? bias[col] : 0.f;
#pragma unroll
            for (int r = 0; r < 4; ++r) {
                int row = m0 + wm*64 + mt*16 + fg*4 + r;
                C[(size_t)row * N + col] = (OutT)(acc[mt][nt][r] + bv);
            }
        }
}

// ---------------------------------------------------------------------------
// V [B,S,H*D] (f16) -> Vt [B*H, D, S] (f16), LDS-tiled 64x64 transpose
__global__ __launch_bounds__(256) void transpose_v(
    const _Float16* __restrict__ V, _Float16* __restrict__ Vt)
{
    __shared__ __align__(16) _Float16 t[64][72];
    const int bh = blockIdx.z;
    const int b = bh >> 4, h = bh & 15;
    const int s0 = blockIdx.x * 64, d0 = blockIdx.y * 64;
    const int tid = threadIdx.x;
#pragma unroll
    for (int i = 0; i < 2; ++i) {
        int e = (i*256 + tid) * 8;
        int row = e >> 6, col = e & 63;           // row = s, col = d
        *(half8*)&t[row][col] =
            *(const half8*)&V[(size_t)(b*S_ + s0 + row) * E_ + h*D_ + d0 + col];
    }
    __syncthreads();
#pragma unroll
    for (int i = 0; i < 2; ++i) {
        int e = (i*256 + tid) * 8;
        int dr = e >> 6, col = e & 63;            // dr = d, col = s
        half8 v;
#pragma unroll
        for (int j = 0; j < 8; ++j) v[j] = t[col + j][dr];
        *(half8*)&Vt[((size_t)bh * D_ + d0 + dr) * S_ + s0 + col] = v;
    }
}

// ---------------------------------------------------------------------------
// Block-cooperative causal flash attention (unchanged).
__global__ __launch_bounds__(256, 2) void attn_causal_coop(
    const _Float16* __restrict__ Q, const _Float16* __restrict__ K,
    const _Float16* __restrict__ Vt, _Float16* __restrict__ O)
{
    const int n   = blockIdx.x;
    const int xcd = n & 7;
    const int idx = n >> 3;                    // 0..63
    const int bh  = xcd * 4 + (idx >> 4);      // 4 heads per XCD
    const int j   = idx & 15;                  // panel-pair index 0..15
    const int b = bh >> 4, h = bh & 15;
    const int tid = threadIdx.x, lane = tid & 63, wave = tid >> 6;
    const int fr = lane & 15, fg = lane >> 4;

    __shared__ __align__(16) _Float16 Ks[64*128];    // 16KB, swizzled
    __shared__ __align__(16) _Float16 Vs[128*64];    // 16KB, swizzled
    __shared__ __align__(16) _Float16 Ps[4][32*72];  // per-wave P strip

    const int rhi = (31 - j) * 64 + wave * 16;   // this wave's hi-panel rows
    const int rlo = j * 64 + wave * 16;          // this wave's lo-panel rows
    const int nkt = 32 - j;                      // k-tiles of 64

    // Q fragments: A[m=fr][k=fg*8+..], mt: 0=hi panel, 1=lo panel
    half8 qf[2][4];
    {
        const _Float16* qb0 = Q + ((size_t)(b*S_) + rhi) * E_ + h*D_;
        const _Float16* qb1 = Q + ((size_t)(b*S_) + rlo) * E_ + h*D_;
#pragma unroll
        for (int kk = 0; kk < 4; ++kk) {
            qf[0][kk] = *(const half8*)&qb0[(size_t)fr * E_ + kk*32 + fg*8];
            qf[1][kk] = *(const half8*)&qb1[(size_t)fr * E_ + kk*32 + fg*8];
        }
    }

    float m_i[2][4], l_i[2][4];
    floatx4 o[2][8] = {};
#pragma unroll
    for (int mt = 0; mt < 2; ++mt)
#pragma unroll
        for (int r = 0; r < 4; ++r) { m_i[mt][r] = -INFINITY; l_i[mt][r] = 0.f; }

    const float scale = 0.088388347648318447f;   // 1/sqrt(128)
    const _Float16* kg = K + (size_t)(b*S_) * E_ + h*D_;
    const _Float16* vg = Vt + (size_t)bh * D_ * S_;
    _Float16* ps = &Ps[wave][0];

    for (int jt = 0; jt < nkt; ++jt) {
        __syncthreads();                         // prev iter's LDS reads done
        // ---- stage K tile [64 rows][16 granules] (4 rounds x 4KB) --------
#pragma unroll
        for (int q = 0; q < 4; ++q) {
            int G = q*256 + tid;                 // granule index 0..1023
            int row = G >> 4, slot = G & 15;
            int c = slot ^ (row & 7);            // inverse swizzle on source
            async_copy16(kg + (size_t)(jt*64 + row) * E_ + c*8,
                         &Ks[(q*256 + wave*64) * 8]);
        }
        // ---- stage Vt tile [128 rows][8 granules] (4 rounds x 4KB) -------
#pragma unroll
        for (int q = 0; q < 4; ++q) {
            int G = q*256 + tid;
            int row = G >> 3, slot = G & 7;
            int c = slot ^ (row & 7);
            async_copy16(vg + (size_t)row * S_ + jt*64 + c*8,
                         &Vs[(q*256 + wave*64) * 8]);
        }
        __syncthreads();                         // vmcnt(0) drain -> tiles ready

        const bool lo_act = (jt <= j);

        // ---- S = Q K^T ---------------------------------------------------
        floatx4 sacc[2][4] = {};
#pragma unroll
        for (int kk = 0; kk < 4; ++kk) {
            half8 bf[4];
#pragma unroll
            for (int nt = 0; nt < 4; ++nt)
                bf[nt] = *(const half8*)
                    &Ks[(nt*16 + fr)*128 + (((kk*4 + fg) ^ (fr & 7)) * 8)];
#pragma unroll
            for (int nt = 0; nt < 4; ++nt)
                sacc[0][nt] = __builtin_amdgcn_mfma_f32_16x16x32_f16(
                    qf[0][kk], bf[nt], sacc[0][nt], 0, 0, 0);
            if (lo_act) {
#pragma unroll
                for (int nt = 0; nt < 4; ++nt)
                    sacc[1][nt] = __builtin_amdgcn_mfma_f32_16x16x32_f16(
                        qf[1][kk], bf[nt], sacc[1][nt], 0, 0, 0);
            }
        }

        // ---- online softmax ----------------------------------------------
        const int kc0 = jt*64 + fr;
#pragma unroll
        for (int mt = 0; mt < 2; ++mt) {
            if (mt == 1 && !lo_act) continue;
            const int qr0 = (mt ? rlo : rhi) + fg*4;
            float alpha[4];
#pragma unroll
            for (int r = 0; r < 4; ++r) {
                float mx = -INFINITY;
#pragma unroll
                for (int nt = 0; nt < 4; ++nt) {
                    float s = sacc[mt][nt][r] * scale;
                    s = (kc0 + nt*16 <= qr0 + r) ? s : -INFINITY;
                    sacc[mt][nt][r] = s;
                    mx = fmaxf(mx, s);
                }
                mx = fmaxf(mx, __shfl_xor(mx, 1));
                mx = fmaxf(mx, __shfl_xor(mx, 2));
                mx = fmaxf(mx, __shfl_xor(mx, 4));
                mx = fmaxf(mx, __shfl_xor(mx, 8));
                float mnew = fmaxf(m_i[mt][r], mx);
                alpha[r] = (m_i[mt][r] == -INFINITY) ? 0.f : __expf(m_i[mt][r] - mnew);
                float rs = 0.f;
#pragma unroll
                for (int nt = 0; nt < 4; ++nt) {
                    float p = __expf(sacc[mt][nt][r] - mnew);  // exp(-inf)=0 masks
                    sacc[mt][nt][r] = p;
                    rs += p;
                }
                rs += __shfl_xor(rs, 1);
                rs += __shfl_xor(rs, 2);
                rs += __shfl_xor(rs, 4);
                rs += __shfl_xor(rs, 8);
                l_i[mt][r] = alpha[r] * l_i[mt][r] + rs;
                m_i[mt][r] = mnew;
            }
#pragma unroll
            for (int dt = 0; dt < 8; ++dt)
#pragma unroll
                for (int r = 0; r < 4; ++r) o[mt][dt][r] *= alpha[r];

            // P: C-layout -> A-layout, wave-private LDS strip
#pragma unroll
            for (int nt = 0; nt < 4; ++nt)
#pragma unroll
                for (int r = 0; r < 4; ++r)
                    ps[(mt*16 + fg*4 + r)*72 + nt*16 + fr] = (_Float16)sacc[mt][nt][r];
        }
        __asm__ __volatile__("s_waitcnt lgkmcnt(0)" ::: "memory");

        // ---- O += P · V (Vs rows are B-layout, k = seq contiguous) -------
#pragma unroll
        for (int kk = 0; kk < 2; ++kk) {
            half8 pf0 = *(const half8*)&ps[(fr)*72 + kk*32 + fg*8];
            half8 pf1 = *(const half8*)&ps[(16 + fr)*72 + kk*32 + fg*8];
#pragma unroll
            for (int dt = 0; dt < 8; ++dt) {
                half8 vf = *(const half8*)
                    &Vs[(dt*16 + fr)*64 + (((kk*4 + fg) ^ (fr & 7)) * 8)];
                o[0][dt] = __builtin_amdgcn_mfma_f32_16x16x32_f16(
                    pf0, vf, o[0][dt], 0, 0, 0);
                if (lo_act)
                    o[1][dt] = __builtin_amdgcn_mfma_f32_16x16x32_f16(
                        pf1, vf, o[1][dt], 0, 0, 0);
            }
        }
    }

    // ---- epilogue ---------------------------------------------------------
#pragma unroll
    for (int mt = 0; mt < 2; ++mt) {
        const int rbase = mt ? rlo : rhi;
        _Float16* ob = O + ((size_t)(b*S_) + rbase) * E_ + h*D_;
#pragma unroll
        for (int r = 0; r < 4; ++r) {
            float inv = 1.f / l_i[mt][r];
#pragma unroll
            for (int dt = 0; dt < 8; ++dt)
                ob[(size_t)(fg*4 + r) * E_ + dt*16 + fr] = (_Float16)(o[mt][dt][r] * inv);
        }
    }
}

// ---------------------------------------------------------------------------
extern "C" void kernel_launch(void* const* d_in, const int* in_sizes, int n_in,
                              void* d_out, int out_size, void* d_ws, size_t ws_size,
                              hipStream_t stream) {
    const float* X  = (const float*)d_in[0];
    const float* Wq = (const float*)d_in[1];
    const float* Wk = (const float*)d_in[2];
    const float* Wv = (const float*)d_in[3];
    const float* Wo = (const float*)d_in[4];
    const float* bo = (const float*)d_in[5];
    float* out = (float*)d_out;

    const size_t ME = (size_t)M_ * E_;   // 8,388,608
    const size_t EE = (size_t)E_ * E_;   // 4,194,304
    _Float16* ws  = (_Float16*)d_ws;
    _Float16* Xh  = ws;
    _Float16* Wqh = Xh  + ME;
    _Float16* Wkh = Wqh + EE;
    _Float16* Wvh = Wkh + EE;
    _Float16* Woh = Wvh + EE;
    _Float16* Qh  = Woh + EE;
    _Float16* Kh  = Qh  + ME;
    _Float16* Vh  = Kh  + ME;
    _Float16* Vth = Xh;   // Xh dead after the QKV GEMMs
    _Float16* Oh  = Vh;   // V dead after the transpose

    cast_all<<<dim3(ME/4/256, 1, 5), dim3(256), 0, stream>>>(
        X, Wq, Wk, Wv, Wo, Xh, Wqh, Wkh, Wvh, Woh);

    gemm_bt<false, _Float16, 3><<<dim3(256, 3), dim3(512), 0, stream>>>(
        Xh, Wqh, Wkh, Wvh, Qh, Kh, Vh, nullptr, M_, E_, E_);

    transpose_v<<<dim3(S_/64, D_/64, B_*H_), dim3(256), 0, stream>>>(Vh, Vth);

    attn_causal_coop<<<dim3(512), dim3(256), 0, stream>>>(Qh, Kh, Vth, Oh);

    gemm_bt<true, float, 1><<<dim3(256, 1), dim3(512), 0, stream>>>(
        Oh, Woh, nullptr, nullptr, out, nullptr, nullptr, bo, M_, E_, E_);
}